// Round 20
// baseline (132.660 us; speedup 1.0000x reference)
//
#include <hip/hip_runtime.h>
#include <hip/hip_bf16.h>
#include <math.h>

// SimCLR NT-Xent: B=4096, D=256, n=8192, T=0.5.
// z' = sqrt(K1) * rownorm(concat(a,b)) as bf16, row-swizzled in global:
//   stored_byte_in_row = logical_byte ^ ((row&7)<<4)
// MFMA(z', z'^T) = K1 * dot -> exp(sim) = exp2(MFMA out).  E SYMMETRIC.
// Round 20 = R16 cover/flush logic, but B REG-STAGED FROM L2 (no LDS data
// path at all): zb (4MB) is L2-resident; bA/bB double-buffered registers,
// loads for phase p+1 issued before phase p's MFMA cluster (compiler emits
// counted vmcnt). Deletes global_load_lds, ds_reads, vmcnt drains, and the
// stage->drain->barrier convoy that cost ~650 cyc/JT. Only remaining
// barrier: per-JT cred (col-sum) aggregation — lgkm-only fence, global
// loads stay in flight across it. R1's no-LDS failure was latency/ILP
// (serial loads, 8 waves/CU); here: batched independent loads + 12
// waves/CU + branch-free flush.
// loss = mean( ln2 * (log2(S_i - exp2(self_i)) - K1*posdot_i) ).

#define NROWS 8192
#define BHALF 4096
#define DDIM  256
#define ROWB  512                 // bytes per bf16 row
#define SSTRIDE 64                // s_part row stride (floats) = slot count

#define SQRT_K1 1.6986436f        // sqrt(2*log2(e))
#define LN2F 0.6931471805599453f

typedef __attribute__((ext_vector_type(8))) __bf16 bf16x8;
typedef __attribute__((ext_vector_type(4))) float f32x4;

#if __has_builtin(__builtin_amdgcn_exp2f)
#define FEXP2(x) __builtin_amdgcn_exp2f(x)
#else
#define FEXP2(x) __exp2f(x)
#endif
#if __has_builtin(__builtin_amdgcn_logf)
#define FLOG2(x) __builtin_amdgcn_logf(x)
#else
#define FLOG2(x) __log2f(x)
#endif

__device__ __forceinline__ float bfu(unsigned short u) {
  union { unsigned v; float f; } x; x.v = ((unsigned)u) << 16; return x.f;
}

// ---------------- Kernel 1: normalize+scale rows -> swizzled bf16 ----------
__global__ __launch_bounds__(256) void norm_kernel(
    const float* __restrict__ a, const float* __restrict__ b,
    char* __restrict__ zb, float* __restrict__ selfdot) {
  int row = blockIdx.x * 4 + (threadIdx.x >> 6);
  int lane = threadIdx.x & 63;
  const float* src = (row < BHALF) ? (a + (size_t)row * DDIM)
                                   : (b + (size_t)(row - BHALF) * DDIM);
  float4 v = ((const float4*)src)[lane];
  float ss = v.x * v.x + v.y * v.y + v.z * v.z + v.w * v.w;
  #pragma unroll
  for (int m = 1; m < 64; m <<= 1) ss += __shfl_xor(ss, m, 64);
  float inv = rsqrtf(ss);
  inv = inv * (1.5f - 0.5f * ss * inv * inv);
  float sc = inv * SQRT_K1;

  union { __hip_bfloat16 h; unsigned short u; } c0, c1, c2, c3;
  c0.h = __float2bfloat16(v.x * sc);
  c1.h = __float2bfloat16(v.y * sc);
  c2.h = __float2bfloat16(v.z * sc);
  c3.h = __float2bfloat16(v.w * sc);
  float q0 = bfu(c0.u), q1 = bfu(c1.u), q2 = bfu(c2.u), q3 = bfu(c3.u);
  float sq = q0 * q0 + q1 * q1 + q2 * q2 + q3 * q3;
  #pragma unroll
  for (int m = 1; m < 64; m <<= 1) sq += __shfl_xor(sq, m, 64);

  ushort4 o = make_ushort4(c0.u, c1.u, c2.u, c3.u);
  int off = row * ROWB + ((lane * 8) ^ ((row & 7) << 4));
  *(ushort4*)(zb + off) = o;
  if (lane == 0) selfdot[row] = sq;
}

// ---------------- Kernel 2: triangular z z^T + exp2 sums, reg-staged B -----
// Grid (64, 11): t = x (128-row strip), b = y (3 squares d=3b..3b+2).
// 256 thr = 4 waves x 32 rows (rf=2). 3 blocks/CU (tiny LDS; ~160 VGPR).
__global__ __launch_bounds__(256, 3) void sim_kernel(
    const char* __restrict__ zb, float* __restrict__ s_part) {
  __shared__ float cred[2][4][32];                // 1 KiB, parity-banked

  int t = blockIdx.x;              // 0..63
  int b = blockIdx.y;              // 0..10

  int wave = threadIdx.x >> 6;
  int lane = threadIdx.x & 63;
  int lrow = lane & 15;
  int kgrp = lane >> 4;
  int sw = (lrow & 7) << 4;
  int r0 = t * 128 + wave * 32;

  int koff[8];
  #pragma unroll
  for (int kk = 0; kk < 8; ++kk) koff[kk] = (kk * 64 + kgrp * 16) ^ sw;

  // --- preload A fragments (32 rows x K=256): 64 VGPRs ---
  bf16x8 af[2][8];
  #pragma unroll
  for (int rf = 0; rf < 2; ++rf) {
    const char* rp = zb + (size_t)(r0 + rf * 16 + lrow) * ROWB;
    #pragma unroll
    for (int kk = 0; kk < 8; ++kk)
      af[rf][kk] = *(const bf16x8*)(rp + koff[kk]);
  }

  float sacc[2][4] = {};
  float cacc[2] = {};
  f32x4 C0, C1;
  bf16x8 bA[8], bB[8];             // double-buffered B fragments (64 VGPR)

  // load the 8 B-fragments of 16 cols (colbase + ct*16) into DST
  #define LOADF(DST, colbase, ct) do {                                        \
    const char* rp_ = zb + (size_t)((colbase) + (ct) * 16 + lrow) * ROWB;     \
    _Pragma("unroll")                                                         \
    for (int kk = 0; kk < 8; ++kk)                                            \
      DST[kk] = *(const bf16x8*)(rp_ + koff[kk]);                             \
  } while (0)

  #define MFMA16(BV) do {                                                     \
    C0 = (f32x4){0.f, 0.f, 0.f, 0.f};                                         \
    C1 = (f32x4){0.f, 0.f, 0.f, 0.f};                                         \
    __builtin_amdgcn_s_setprio(1);                                            \
    _Pragma("unroll")                                                         \
    for (int kk = 0; kk < 8; ++kk) {                                          \
      C0 = __builtin_amdgcn_mfma_f32_16x16x32_bf16(af[0][kk], BV[kk], C0, 0, 0, 0); \
      C1 = __builtin_amdgcn_mfma_f32_16x16x32_bf16(af[1][kk], BV[kk], C1, 0, 0, 0); \
    }                                                                         \
    __builtin_amdgcn_s_setprio(0);                                            \
  } while (0)

  #define FLUSHC(ct) do {                                                     \
    float cs = 0.f;                                                           \
    _Pragma("unroll")                                                         \
    for (int r = 0; r < 4; ++r) {                                             \
      float e0 = FEXP2(C0[r]), e1 = FEXP2(C1[r]);                             \
      sacc[0][r] += e0; sacc[1][r] += e1;                                     \
      cs += e0 + e1;                                                          \
    }                                                                         \
    cacc[ct] += cs;                                                           \
  } while (0)

  // colbase of JT q (q = 0..11): d = 3b + (q>>2), chunk j = q&3
  #define COLBASE(q) ((((t + 3 * b + ((q) >> 2)) & 63) << 7) + (((q) & 3) << 5))

  // prologue: load JT0/ct0 fragments
  LOADF(bA, COLBASE(0), 0);

  for (int jt = 0; jt < 12; ++jt) {
    int d = 3 * b + (jt >> 2);
    int u = (t + d) & 63;
    bool last = (jt == 11);
    int colbase = COLBASE(jt);

    // ---- phase 0: prefetch ct1 -> bB, MFMA on bA ----
    LOADF(bB, colbase, 1);
    MFMA16(bA);
    FLUSHC(0);
    // ---- phase 1: prefetch next JT ct0 -> bA, MFMA on bB ----
    if (!last) {
      int nb = COLBASE(jt + 1);
      LOADF(bA, nb, 0);
    }
    MFMA16(bB);
    FLUSHC(1);

    // ---- per-JT bookkeeping ----
    bool harvest = (d >= 1) && (d <= 31);   // two-sided squares only
    if (harvest) {
      #pragma unroll
      for (int c2 = 0; c2 < 2; ++c2) {
        float v = cacc[c2];
        v += __shfl_xor(v, 16, 64);
        v += __shfl_xor(v, 32, 64);
        if (kgrp == 0) cred[jt & 1][wave][c2 * 16 + lrow] = v;
      }
    }
    cacc[0] = 0.f; cacc[1] = 0.f;

    if ((jt & 3) == 3) {                    // square end: row flush, slot d
      #pragma unroll
      for (int rf = 0; rf < 2; ++rf) {
        #pragma unroll
        for (int r = 0; r < 4; ++r) {
          float v = sacc[rf][r];
          #pragma unroll
          for (int m = 1; m < 16; m <<= 1) v += __shfl_xor(v, m, 64);
          if (lrow == 0) {
            int grow = r0 + rf * 16 + kgrp * 4 + r;
            s_part[(size_t)grow * SSTRIDE + d] = v;
          }
          sacc[rf][r] = 0.f;
        }
      }
    }

    // cred visibility only: lgkm fence + barrier (global loads fly across)
    asm volatile("s_waitcnt lgkmcnt(0)" ::: "memory");
    __builtin_amdgcn_sched_barrier(0);
    __builtin_amdgcn_s_barrier();

    // post-barrier: one wave writes this JT's 32 col-sums (slot 32+d)
    if (harvest && wave == (jt & 3) && lane < 32) {
      int colrow = u * 128 + (jt & 3) * 32 + lane;
      float v = cred[jt & 1][0][lane] + cred[jt & 1][1][lane] +
                cred[jt & 1][2][lane] + cred[jt & 1][3][lane];
      s_part[(size_t)colrow * SSTRIDE + 32 + d] = v;
    }
  }
  #undef COLBASE
  #undef FLUSHC
  #undef MFMA16
  #undef LOADF
}

// ---------------- Kernel 3: per-row term (pos dot + assemble) --------------
// 512 blocks x 4 waves x 4 rows.
__global__ __launch_bounds__(256) void rowterm_kernel(
    const char* __restrict__ zb, const float* __restrict__ s_part,
    const float* __restrict__ selfdot, float* __restrict__ bpart) {
  int wave = threadIdx.x >> 6;
  int lane = threadIdx.x & 63;
  int rbase = blockIdx.x * 16 + wave * 4;
  float wacc = 0.f;
  #pragma unroll
  for (int rr = 0; rr < 4; ++rr) {
    int i = rbase + rr;
    int j = i ^ BHALF;                       // (i+B) mod 2B
    int wo = (lane * 8) ^ ((i & 7) << 4);    // j&7 == i&7 (4096 % 8 == 0)
    ushort4 zi = *(const ushort4*)(zb + (size_t)i * ROWB + wo);
    ushort4 zj = *(const ushort4*)(zb + (size_t)j * ROWB + wo);
    float dot = bfu(zi.x) * bfu(zj.x) + bfu(zi.y) * bfu(zj.y) +
                bfu(zi.z) * bfu(zj.z) + bfu(zi.w) * bfu(zj.w);
    float sp = s_part[(size_t)i * SSTRIDE + lane];   // all 64 slots, coalesced
    #pragma unroll
    for (int m = 1; m < 64; m <<= 1) {
      dot += __shfl_xor(dot, m, 64);
      sp += __shfl_xor(sp, m, 64);
    }
    float S = sp - FEXP2(selfdot[i]);          // remove diagonal
    wacc += LN2F * (FLOG2(S) - dot);           // denom - pos (2's cancel)
  }
  __shared__ float red[4];
  if (lane == 0) red[wave] = wacc;
  __syncthreads();
  if (threadIdx.x == 0)
    bpart[blockIdx.x] = red[0] + red[1] + red[2] + red[3];
}

// ---------------- Kernel 4: final sum --------------------------------------
__global__ __launch_bounds__(512) void final_kernel(
    const float* __restrict__ bpart, float* __restrict__ out) {
  int t = threadIdx.x;  // 512 threads = 8 waves
  float v = bpart[t];
  #pragma unroll
  for (int m = 1; m < 64; m <<= 1) v += __shfl_xor(v, m, 64);
  __shared__ float r2[8];
  if ((t & 63) == 0) r2[t >> 6] = v;
  __syncthreads();
  if (t == 0) {
    float s = 0.f;
    #pragma unroll
    for (int w = 0; w < 8; ++w) s += r2[w];
    out[0] = s / (float)NROWS;
  }
}

// ---------------- Launcher --------------------------------------------------
extern "C" void kernel_launch(void* const* d_in, const int* in_sizes, int n_in,
                              void* d_out, int out_size, void* d_ws, size_t ws_size,
                              hipStream_t stream) {
  const float* a = (const float*)d_in[0];
  const float* b = (const float*)d_in[1];
  float* out = (float*)d_out;
  char* ws = (char*)d_ws;

  char* zb = ws;                                            // 4 MiB
  float* selfdot = (float*)(ws + (size_t)NROWS * ROWB);     // 32 KiB
  float* s_part = selfdot + NROWS;                          // 2 MiB [8192][64]
  float* bpart = s_part + (size_t)NROWS * SSTRIDE;          // 2 KiB

  hipLaunchKernelGGL(norm_kernel, dim3(NROWS / 4), dim3(256), 0, stream,
                     a, b, zb, selfdot);
  hipLaunchKernelGGL(sim_kernel, dim3(64, 11), dim3(256), 0, stream,
                     zb, s_part);
  hipLaunchKernelGGL(rowterm_kernel, dim3(512), dim3(256), 0, stream,
                     zb, s_part, selfdot, bpart);
  hipLaunchKernelGGL(final_kernel, dim3(1), dim3(512), 0, stream, bpart, out);
}

// Round 21
// 57.617 us; speedup vs baseline: 2.3024x; 2.3024x over previous
//
#include <hip/hip_runtime.h>
#include <hip/hip_bf16.h>
#include <math.h>

// SimCLR NT-Xent: B=4096, D=256, n=8192, T=0.5.
// z' = sqrt(K1) * rownorm(concat(a,b)) as bf16, row-swizzled in global:
//   stored_byte_in_row = logical_byte ^ ((row&7)<<4)
// MFMA(z', z'^T) = K1 * dot -> exp(sim) = exp2(MFMA out).  E SYMMETRIC.
// Round 21 = R16 verbatim (session best, 42.25 us) + fused deterministic
// finalize (verified in R19 independently of that round's sim spill):
// rowterm blocks add their partial loss via int64 fixed-point atomicAdd
// (integer adds commute -> bitwise deterministic), last block (atomic
// counter) writes out[0]. Removes the final_kernel launch + gap.
// Triangular cover: 64 strips x 11 blocks x 3 squares (128x128, d=3b..3b+2);
// d=0 diag row-only, d=32 antipodal row-only both sides, d=1..31 two-sided
// (row slot d, col slot 32+d) -> 64 slots/row, each written exactly once.
// loss = mean( ln2 * (log2(S_i - exp2(self_i)) - K1*posdot_i) ).

#define NROWS 8192
#define BHALF 4096
#define DDIM  256
#define ROWB  512                 // bytes per bf16 row
#define JT    32                  // cols per JT-tile
#define TILEB (JT * ROWB)         // 16 KiB per LDS buffer
#define SSTRIDE 64                // s_part row stride (floats) = slot count

#define SQRT_K1 1.6986436f        // sqrt(2*log2(e))
#define LN2F 0.6931471805599453f
#define FIXSCALE 1099511627776.0  // 2^40

typedef __attribute__((ext_vector_type(8))) __bf16 bf16x8;
typedef __attribute__((ext_vector_type(4))) float f32x4;

#if __has_builtin(__builtin_amdgcn_exp2f)
#define FEXP2(x) __builtin_amdgcn_exp2f(x)
#else
#define FEXP2(x) __exp2f(x)
#endif
#if __has_builtin(__builtin_amdgcn_logf)
#define FLOG2(x) __builtin_amdgcn_logf(x)
#else
#define FLOG2(x) __log2f(x)
#endif

__device__ __forceinline__ float bfu(unsigned short u) {
  union { unsigned v; float f; } x; x.v = ((unsigned)u) << 16; return x.f;
}

// ---------------- Kernel 1: normalize+scale rows -> swizzled bf16 ----------
__global__ __launch_bounds__(256) void norm_kernel(
    const float* __restrict__ a, const float* __restrict__ b,
    char* __restrict__ zb, float* __restrict__ selfdot) {
  int row = blockIdx.x * 4 + (threadIdx.x >> 6);
  int lane = threadIdx.x & 63;
  const float* src = (row < BHALF) ? (a + (size_t)row * DDIM)
                                   : (b + (size_t)(row - BHALF) * DDIM);
  float4 v = ((const float4*)src)[lane];
  float ss = v.x * v.x + v.y * v.y + v.z * v.z + v.w * v.w;
  #pragma unroll
  for (int m = 1; m < 64; m <<= 1) ss += __shfl_xor(ss, m, 64);
  float inv = rsqrtf(ss);
  inv = inv * (1.5f - 0.5f * ss * inv * inv);
  float sc = inv * SQRT_K1;

  union { __hip_bfloat16 h; unsigned short u; } c0, c1, c2, c3;
  c0.h = __float2bfloat16(v.x * sc);
  c1.h = __float2bfloat16(v.y * sc);
  c2.h = __float2bfloat16(v.z * sc);
  c3.h = __float2bfloat16(v.w * sc);
  float q0 = bfu(c0.u), q1 = bfu(c1.u), q2 = bfu(c2.u), q3 = bfu(c3.u);
  float sq = q0 * q0 + q1 * q1 + q2 * q2 + q3 * q3;
  #pragma unroll
  for (int m = 1; m < 64; m <<= 1) sq += __shfl_xor(sq, m, 64);

  ushort4 o = make_ushort4(c0.u, c1.u, c2.u, c3.u);
  int off = row * ROWB + ((lane * 8) ^ ((row & 7) << 4));
  *(ushort4*)(zb + off) = o;
  if (lane == 0) selfdot[row] = sq;
}

// ---------------- Kernel 2: triangular z z^T + exp2 sums, 3 blocks/CU ------
// Grid (64, 11): t = x (128-row strip), b = y (3 squares d=3b..3b+2).
// 256 thr = 4 waves x 32 rows (rf=2).  [R16 verbatim]
__global__ __launch_bounds__(256, 3) void sim_kernel(
    const char* __restrict__ zb, float* __restrict__ s_part) {
  __shared__ __align__(16) char lds[2 * TILEB];   // 32 KiB double buffer
  __shared__ float cred[2][4][32];                // 1 KiB, parity-banked

  int t = blockIdx.x;              // 0..63
  int b = blockIdx.y;              // 0..10

  int wave = threadIdx.x >> 6;
  int lane = threadIdx.x & 63;
  int lrow = lane & 15;
  int kgrp = lane >> 4;
  int sw = (lrow & 7) << 4;
  int r0 = t * 128 + wave * 32;

  // --- preload A fragments (32 rows x K=256): 64 VGPRs ---
  bf16x8 af[2][8];
  #pragma unroll
  for (int rf = 0; rf < 2; ++rf) {
    const char* rp = zb + (size_t)(r0 + rf * 16 + lrow) * ROWB;
    #pragma unroll
    for (int kk = 0; kk < 8; ++kk)
      af[rf][kk] = *(const bf16x8*)(rp + ((kk * 64 + kgrp * 16) ^ sw));
  }

  float sacc[2][4] = {};
  float cacc[2] = {};
  f32x4 C0, C1;
  bf16x8 bfv[8];

  // stage slot s = wave*4+i (ct = s>>3, kk = s&7) of a 32-col tile
  #define STAGE_SLOT(dstbuf, colbase, i) do {                                 \
    int s_ = wave * 4 + (i);                                                  \
    const char* g_ = zb +                                                     \
        (size_t)((colbase) + (s_ >> 3) * 16 + lrow) * ROWB +                  \
        ((((s_ & 7) * 64) + kgrp * 16) ^ sw);                                 \
    char* l_ = lds + (dstbuf) * TILEB + s_ * 1024;                            \
    __builtin_amdgcn_global_load_lds(                                         \
        (const __attribute__((address_space(1))) void*)g_,                    \
        (__attribute__((address_space(3))) void*)l_, 16, 0, 0);               \
  } while (0)

  #define DSREAD(bufi, ct) do {                                               \
    const char* lbr = lds + (bufi) * TILEB + lane * 16;                       \
    _Pragma("unroll")                                                         \
    for (int kk = 0; kk < 8; ++kk)                                            \
      bfv[kk] = *(const bf16x8*)(lbr + ((ct) * 8 + kk) * 1024);               \
  } while (0)

  #define MFMA16() do {                                                       \
    C0 = (f32x4){0.f, 0.f, 0.f, 0.f};                                         \
    C1 = (f32x4){0.f, 0.f, 0.f, 0.f};                                         \
    __builtin_amdgcn_s_setprio(1);                                            \
    _Pragma("unroll")                                                         \
    for (int kk = 0; kk < 8; ++kk) {                                          \
      C0 = __builtin_amdgcn_mfma_f32_16x16x32_bf16(af[0][kk], bfv[kk], C0, 0, 0, 0); \
      C1 = __builtin_amdgcn_mfma_f32_16x16x32_bf16(af[1][kk], bfv[kk], C1, 0, 0, 0); \
    }                                                                         \
    __builtin_amdgcn_s_setprio(0);                                            \
  } while (0)

  #define FLUSHC(ct) do {                                                     \
    float cs = 0.f;                                                           \
    _Pragma("unroll")                                                         \
    for (int r = 0; r < 4; ++r) {                                             \
      float e0 = FEXP2(C0[r]), e1 = FEXP2(C1[r]);                             \
      sacc[0][r] += e0; sacc[1][r] += e1;                                     \
      cs += e0 + e1;                                                          \
    }                                                                         \
    cacc[ct] += cs;                                                           \
  } while (0)

  // colbase of JT q (q = 0..11): d = 3b + (q>>2), chunk j = q&3
  #define COLBASE(q) ((((t + 3 * b + ((q) >> 2)) & 63) << 7) + (((q) & 3) << 5))

  // prologue: stage JT 0 (4 slots per wave), drain, barrier
  {
    int cb0 = COLBASE(0);
    #pragma unroll
    for (int i = 0; i < 4; ++i) STAGE_SLOT(0, cb0, i);
  }
  asm volatile("s_waitcnt vmcnt(0)" ::: "memory");
  __builtin_amdgcn_sched_barrier(0);
  __builtin_amdgcn_s_barrier();

  for (int jt = 0; jt < 12; ++jt) {
    int buf = jt & 1;
    int d = 3 * b + (jt >> 2);
    int u = (t + d) & 63;
    bool last = (jt == 11);
    int nextbase = last ? 0 : COLBASE(jt + 1);

    // ---- phase 0 ----
    DSREAD(buf, 0);
    if (!last) {
      STAGE_SLOT(buf ^ 1, nextbase, 0);
      STAGE_SLOT(buf ^ 1, nextbase, 1);
    }
    MFMA16();
    FLUSHC(0);
    // ---- phase 1 ----
    DSREAD(buf, 1);
    if (!last) {
      STAGE_SLOT(buf ^ 1, nextbase, 2);
      STAGE_SLOT(buf ^ 1, nextbase, 3);
    }
    MFMA16();
    FLUSHC(1);

    // ---- per-JT bookkeeping ----
    bool harvest = (d >= 1) && (d <= 31);   // two-sided squares only
    if (harvest) {
      #pragma unroll
      for (int c2 = 0; c2 < 2; ++c2) {
        float v = cacc[c2];
        v += __shfl_xor(v, 16, 64);
        v += __shfl_xor(v, 32, 64);
        if (kgrp == 0) cred[jt & 1][wave][c2 * 16 + lrow] = v;
      }
    }
    cacc[0] = 0.f; cacc[1] = 0.f;

    if ((jt & 3) == 3) {                    // square end: row flush, slot d
      #pragma unroll
      for (int rf = 0; rf < 2; ++rf) {
        #pragma unroll
        for (int r = 0; r < 4; ++r) {
          float v = sacc[rf][r];
          #pragma unroll
          for (int m = 1; m < 16; m <<= 1) v += __shfl_xor(v, m, 64);
          if (lrow == 0) {
            int grow = r0 + rf * 16 + kgrp * 4 + r;
            s_part[(size_t)grow * SSTRIDE + d] = v;
          }
          sacc[rf][r] = 0.f;
        }
      }
    }

    asm volatile("s_waitcnt vmcnt(0) lgkmcnt(0)" ::: "memory");
    __builtin_amdgcn_sched_barrier(0);
    __builtin_amdgcn_s_barrier();

    // post-barrier: one wave writes this JT's 32 col-sums (slot 32+d)
    if (harvest && wave == (jt & 3) && lane < 32) {
      int colrow = u * 128 + (jt & 3) * 32 + lane;
      float v = cred[jt & 1][0][lane] + cred[jt & 1][1][lane] +
                cred[jt & 1][2][lane] + cred[jt & 1][3][lane];
      s_part[(size_t)colrow * SSTRIDE + 32 + d] = v;
    }
  }
  #undef COLBASE
  #undef FLUSHC
  #undef MFMA16
  #undef DSREAD
  #undef STAGE_SLOT
}

// ---------------- Kernel 3: per-row term + fused deterministic finalize ----
// 512 blocks x 4 waves x 4 rows. Block sums -> int64 fixed-point atomicAdd
// (order-independent => bitwise deterministic); last block writes out.
__global__ __launch_bounds__(256) void rowterm_kernel(
    const char* __restrict__ zb, const float* __restrict__ s_part,
    const float* __restrict__ selfdot, unsigned long long* __restrict__ accum,
    unsigned int* __restrict__ counter, float* __restrict__ out) {
  int wave = threadIdx.x >> 6;
  int lane = threadIdx.x & 63;
  int rbase = blockIdx.x * 16 + wave * 4;
  float wacc = 0.f;
  #pragma unroll
  for (int rr = 0; rr < 4; ++rr) {
    int i = rbase + rr;
    int j = i ^ BHALF;                       // (i+B) mod 2B
    int wo = (lane * 8) ^ ((i & 7) << 4);    // j&7 == i&7 (4096 % 8 == 0)
    ushort4 zi = *(const ushort4*)(zb + (size_t)i * ROWB + wo);
    ushort4 zj = *(const ushort4*)(zb + (size_t)j * ROWB + wo);
    float dot = bfu(zi.x) * bfu(zj.x) + bfu(zi.y) * bfu(zj.y) +
                bfu(zi.z) * bfu(zj.z) + bfu(zi.w) * bfu(zj.w);
    float sp = s_part[(size_t)i * SSTRIDE + lane];   // all 64 slots, coalesced
    #pragma unroll
    for (int m = 1; m < 64; m <<= 1) {
      dot += __shfl_xor(dot, m, 64);
      sp += __shfl_xor(sp, m, 64);
    }
    float S = sp - FEXP2(selfdot[i]);          // remove diagonal
    wacc += LN2F * (FLOG2(S) - dot);           // denom - pos (2's cancel)
  }
  __shared__ float red[4];
  if (lane == 0) red[wave] = wacc;
  __syncthreads();
  if (threadIdx.x == 0) {
    float bsum = red[0] + red[1] + red[2] + red[3];
    long long q = (long long)llrint((double)bsum * FIXSCALE);
    atomicAdd(accum, (unsigned long long)q);
    __threadfence();
    unsigned int prev = atomicAdd(counter, 1u);
    if (prev == 511u) {
      unsigned long long s = atomicAdd(accum, 0ull);   // coherent read
      out[0] = (float)((double)(long long)s / FIXSCALE / (double)NROWS);
    }
  }
}

// ---------------- Launcher --------------------------------------------------
extern "C" void kernel_launch(void* const* d_in, const int* in_sizes, int n_in,
                              void* d_out, int out_size, void* d_ws, size_t ws_size,
                              hipStream_t stream) {
  const float* a = (const float*)d_in[0];
  const float* b = (const float*)d_in[1];
  float* out = (float*)d_out;
  char* ws = (char*)d_ws;

  char* zb = ws;                                              // 4 MiB
  float* selfdot = (float*)(ws + (size_t)NROWS * ROWB);       // 32 KiB
  float* s_part = selfdot + NROWS;                            // 2 MiB
  char* tail = (char*)(s_part + (size_t)NROWS * SSTRIDE);     // 16 B
  unsigned long long* accum = (unsigned long long*)tail;
  unsigned int* counter = (unsigned int*)(tail + 8);

  hipMemsetAsync(tail, 0, 16, stream);   // reset accum+counter every call
  hipLaunchKernelGGL(norm_kernel, dim3(NROWS / 4), dim3(256), 0, stream,
                     a, b, zb, selfdot);
  hipLaunchKernelGGL(sim_kernel, dim3(64, 11), dim3(256), 0, stream,
                     zb, s_part);
  hipLaunchKernelGGL(rowterm_kernel, dim3(512), dim3(256), 0, stream,
                     zb, s_part, selfdot, accum, counter, out);
}

// Round 22
// 41.959 us; speedup vs baseline: 3.1616x; 1.3732x over previous
//
#include <hip/hip_runtime.h>
#include <hip/hip_bf16.h>
#include <math.h>

// SimCLR NT-Xent: B=4096, D=256, n=8192, T=0.5.
// z' = sqrt(K1) * rownorm(concat(a,b)) as bf16, row-swizzled in global:
//   stored_byte_in_row = logical_byte ^ ((row&7)<<4)
// MFMA(z', z'^T) = K1 * dot -> exp(sim) = exp2(MFMA out).  E SYMMETRIC.
// FINAL (= R16, session best 42.25 us): triangular circulant cover at
// 128x128 (half the MFMA, 3% redundancy), rf=2 fragment-order LDS (zero
// bank conflicts), 3 blocks/CU, fine 2-phase pipeline, exp2-folded
// epilogue, 64-slot once-written harvest.
//   Cover: 64 strips x 11 blocks x 3 squares (d=3b..3b+2); d=0 diag
//   row-only, d=32 antipodal row-only both sides, d=1..31 two-sided
//   (row slot d, col slot 32+d) -> 64 slots/row, each written exactly once.
// R17-R21 variants (8-phase port, 32x32 MFMA, 4 blk/CU, reg-staged B,
// fused finalize+memset) all regressed: spill / L2-thrash / dispatch cost.
// loss = mean( ln2 * (log2(S_i - exp2(self_i)) - K1*posdot_i) ).

#define NROWS 8192
#define BHALF 4096
#define DDIM  256
#define ROWB  512                 // bytes per bf16 row
#define JT    32                  // cols per JT-tile
#define TILEB (JT * ROWB)         // 16 KiB per LDS buffer
#define SSTRIDE 64                // s_part row stride (floats) = slot count

#define SQRT_K1 1.6986436f        // sqrt(2*log2(e))
#define LN2F 0.6931471805599453f

typedef __attribute__((ext_vector_type(8))) __bf16 bf16x8;
typedef __attribute__((ext_vector_type(4))) float f32x4;

#if __has_builtin(__builtin_amdgcn_exp2f)
#define FEXP2(x) __builtin_amdgcn_exp2f(x)
#else
#define FEXP2(x) __exp2f(x)
#endif
#if __has_builtin(__builtin_amdgcn_logf)
#define FLOG2(x) __builtin_amdgcn_logf(x)
#else
#define FLOG2(x) __log2f(x)
#endif

__device__ __forceinline__ float bfu(unsigned short u) {
  union { unsigned v; float f; } x; x.v = ((unsigned)u) << 16; return x.f;
}

// ---------------- Kernel 1: normalize+scale rows -> swizzled bf16 ----------
__global__ __launch_bounds__(256) void norm_kernel(
    const float* __restrict__ a, const float* __restrict__ b,
    char* __restrict__ zb, float* __restrict__ selfdot) {
  int row = blockIdx.x * 4 + (threadIdx.x >> 6);
  int lane = threadIdx.x & 63;
  const float* src = (row < BHALF) ? (a + (size_t)row * DDIM)
                                   : (b + (size_t)(row - BHALF) * DDIM);
  float4 v = ((const float4*)src)[lane];
  float ss = v.x * v.x + v.y * v.y + v.z * v.z + v.w * v.w;
  #pragma unroll
  for (int m = 1; m < 64; m <<= 1) ss += __shfl_xor(ss, m, 64);
  float inv = rsqrtf(ss);
  inv = inv * (1.5f - 0.5f * ss * inv * inv);
  float sc = inv * SQRT_K1;

  union { __hip_bfloat16 h; unsigned short u; } c0, c1, c2, c3;
  c0.h = __float2bfloat16(v.x * sc);
  c1.h = __float2bfloat16(v.y * sc);
  c2.h = __float2bfloat16(v.z * sc);
  c3.h = __float2bfloat16(v.w * sc);
  float q0 = bfu(c0.u), q1 = bfu(c1.u), q2 = bfu(c2.u), q3 = bfu(c3.u);
  float sq = q0 * q0 + q1 * q1 + q2 * q2 + q3 * q3;
  #pragma unroll
  for (int m = 1; m < 64; m <<= 1) sq += __shfl_xor(sq, m, 64);

  ushort4 o = make_ushort4(c0.u, c1.u, c2.u, c3.u);
  int off = row * ROWB + ((lane * 8) ^ ((row & 7) << 4));
  *(ushort4*)(zb + off) = o;
  if (lane == 0) selfdot[row] = sq;
}

// ---------------- Kernel 2: triangular z z^T + exp2 sums, 3 blocks/CU ------
// Grid (64, 11): t = x (128-row strip), b = y (3 squares d=3b..3b+2).
// 256 thr = 4 waves x 32 rows (rf=2).
__global__ __launch_bounds__(256, 3) void sim_kernel(
    const char* __restrict__ zb, float* __restrict__ s_part) {
  __shared__ __align__(16) char lds[2 * TILEB];   // 32 KiB double buffer
  __shared__ float cred[2][4][32];                // 1 KiB, parity-banked

  int t = blockIdx.x;              // 0..63
  int b = blockIdx.y;              // 0..10

  int wave = threadIdx.x >> 6;
  int lane = threadIdx.x & 63;
  int lrow = lane & 15;
  int kgrp = lane >> 4;
  int sw = (lrow & 7) << 4;
  int r0 = t * 128 + wave * 32;

  // --- preload A fragments (32 rows x K=256): 64 VGPRs ---
  bf16x8 af[2][8];
  #pragma unroll
  for (int rf = 0; rf < 2; ++rf) {
    const char* rp = zb + (size_t)(r0 + rf * 16 + lrow) * ROWB;
    #pragma unroll
    for (int kk = 0; kk < 8; ++kk)
      af[rf][kk] = *(const bf16x8*)(rp + ((kk * 64 + kgrp * 16) ^ sw));
  }

  float sacc[2][4] = {};
  float cacc[2] = {};
  f32x4 C0, C1;
  bf16x8 bfv[8];

  // stage slot s = wave*4+i (ct = s>>3, kk = s&7) of a 32-col tile
  #define STAGE_SLOT(dstbuf, colbase, i) do {                                 \
    int s_ = wave * 4 + (i);                                                  \
    const char* g_ = zb +                                                     \
        (size_t)((colbase) + (s_ >> 3) * 16 + lrow) * ROWB +                  \
        ((((s_ & 7) * 64) + kgrp * 16) ^ sw);                                 \
    char* l_ = lds + (dstbuf) * TILEB + s_ * 1024;                            \
    __builtin_amdgcn_global_load_lds(                                         \
        (const __attribute__((address_space(1))) void*)g_,                    \
        (__attribute__((address_space(3))) void*)l_, 16, 0, 0);               \
  } while (0)

  #define DSREAD(bufi, ct) do {                                               \
    const char* lbr = lds + (bufi) * TILEB + lane * 16;                       \
    _Pragma("unroll")                                                         \
    for (int kk = 0; kk < 8; ++kk)                                            \
      bfv[kk] = *(const bf16x8*)(lbr + ((ct) * 8 + kk) * 1024);               \
  } while (0)

  #define MFMA16() do {                                                       \
    C0 = (f32x4){0.f, 0.f, 0.f, 0.f};                                         \
    C1 = (f32x4){0.f, 0.f, 0.f, 0.f};                                         \
    __builtin_amdgcn_s_setprio(1);                                            \
    _Pragma("unroll")                                                         \
    for (int kk = 0; kk < 8; ++kk) {                                          \
      C0 = __builtin_amdgcn_mfma_f32_16x16x32_bf16(af[0][kk], bfv[kk], C0, 0, 0, 0); \
      C1 = __builtin_amdgcn_mfma_f32_16x16x32_bf16(af[1][kk], bfv[kk], C1, 0, 0, 0); \
    }                                                                         \
    __builtin_amdgcn_s_setprio(0);                                            \
  } while (0)

  #define FLUSHC(ct) do {                                                     \
    float cs = 0.f;                                                           \
    _Pragma("unroll")                                                         \
    for (int r = 0; r < 4; ++r) {                                             \
      float e0 = FEXP2(C0[r]), e1 = FEXP2(C1[r]);                             \
      sacc[0][r] += e0; sacc[1][r] += e1;                                     \
      cs += e0 + e1;                                                          \
    }                                                                         \
    cacc[ct] += cs;                                                           \
  } while (0)

  // colbase of JT q (q = 0..11): d = 3b + (q>>2), chunk j = q&3
  #define COLBASE(q) ((((t + 3 * b + ((q) >> 2)) & 63) << 7) + (((q) & 3) << 5))

  // prologue: stage JT 0 (4 slots per wave), drain, barrier
  {
    int cb0 = COLBASE(0);
    #pragma unroll
    for (int i = 0; i < 4; ++i) STAGE_SLOT(0, cb0, i);
  }
  asm volatile("s_waitcnt vmcnt(0)" ::: "memory");
  __builtin_amdgcn_sched_barrier(0);
  __builtin_amdgcn_s_barrier();

  for (int jt = 0; jt < 12; ++jt) {
    int buf = jt & 1;
    int d = 3 * b + (jt >> 2);
    int u = (t + d) & 63;
    bool last = (jt == 11);
    int nextbase = last ? 0 : COLBASE(jt + 1);

    // ---- phase 0 ----
    DSREAD(buf, 0);
    if (!last) {
      STAGE_SLOT(buf ^ 1, nextbase, 0);
      STAGE_SLOT(buf ^ 1, nextbase, 1);
    }
    MFMA16();
    FLUSHC(0);
    // ---- phase 1 ----
    DSREAD(buf, 1);
    if (!last) {
      STAGE_SLOT(buf ^ 1, nextbase, 2);
      STAGE_SLOT(buf ^ 1, nextbase, 3);
    }
    MFMA16();
    FLUSHC(1);

    // ---- per-JT bookkeeping ----
    bool harvest = (d >= 1) && (d <= 31);   // two-sided squares only
    if (harvest) {
      #pragma unroll
      for (int c2 = 0; c2 < 2; ++c2) {
        float v = cacc[c2];
        v += __shfl_xor(v, 16, 64);
        v += __shfl_xor(v, 32, 64);
        if (kgrp == 0) cred[jt & 1][wave][c2 * 16 + lrow] = v;
      }
    }
    cacc[0] = 0.f; cacc[1] = 0.f;

    if ((jt & 3) == 3) {                    // square end: row flush, slot d
      #pragma unroll
      for (int rf = 0; rf < 2; ++rf) {
        #pragma unroll
        for (int r = 0; r < 4; ++r) {
          float v = sacc[rf][r];
          #pragma unroll
          for (int m = 1; m < 16; m <<= 1) v += __shfl_xor(v, m, 64);
          if (lrow == 0) {
            int grow = r0 + rf * 16 + kgrp * 4 + r;
            s_part[(size_t)grow * SSTRIDE + d] = v;
          }
          sacc[rf][r] = 0.f;
        }
      }
    }

    asm volatile("s_waitcnt vmcnt(0) lgkmcnt(0)" ::: "memory");
    __builtin_amdgcn_sched_barrier(0);
    __builtin_amdgcn_s_barrier();

    // post-barrier: one wave writes this JT's 32 col-sums (slot 32+d)
    if (harvest && wave == (jt & 3) && lane < 32) {
      int colrow = u * 128 + (jt & 3) * 32 + lane;
      float v = cred[jt & 1][0][lane] + cred[jt & 1][1][lane] +
                cred[jt & 1][2][lane] + cred[jt & 1][3][lane];
      s_part[(size_t)colrow * SSTRIDE + 32 + d] = v;
    }
  }
  #undef COLBASE
  #undef FLUSHC
  #undef MFMA16
  #undef DSREAD
  #undef STAGE_SLOT
}

// ---------------- Kernel 3: per-row term (pos dot + assemble) --------------
// 512 blocks x 4 waves x 4 rows.
__global__ __launch_bounds__(256) void rowterm_kernel(
    const char* __restrict__ zb, const float* __restrict__ s_part,
    const float* __restrict__ selfdot, float* __restrict__ bpart) {
  int wave = threadIdx.x >> 6;
  int lane = threadIdx.x & 63;
  int rbase = blockIdx.x * 16 + wave * 4;
  float wacc = 0.f;
  #pragma unroll
  for (int rr = 0; rr < 4; ++rr) {
    int i = rbase + rr;
    int j = i ^ BHALF;                       // (i+B) mod 2B
    int wo = (lane * 8) ^ ((i & 7) << 4);    // j&7 == i&7 (4096 % 8 == 0)
    ushort4 zi = *(const ushort4*)(zb + (size_t)i * ROWB + wo);
    ushort4 zj = *(const ushort4*)(zb + (size_t)j * ROWB + wo);
    float dot = bfu(zi.x) * bfu(zj.x) + bfu(zi.y) * bfu(zj.y) +
                bfu(zi.z) * bfu(zj.z) + bfu(zi.w) * bfu(zj.w);
    float sp = s_part[(size_t)i * SSTRIDE + lane];   // all 64 slots, coalesced
    #pragma unroll
    for (int m = 1; m < 64; m <<= 1) {
      dot += __shfl_xor(dot, m, 64);
      sp += __shfl_xor(sp, m, 64);
    }
    float S = sp - FEXP2(selfdot[i]);          // remove diagonal
    wacc += LN2F * (FLOG2(S) - dot);           // denom - pos (2's cancel)
  }
  __shared__ float red[4];
  if (lane == 0) red[wave] = wacc;
  __syncthreads();
  if (threadIdx.x == 0)
    bpart[blockIdx.x] = red[0] + red[1] + red[2] + red[3];
}

// ---------------- Kernel 4: final sum --------------------------------------
__global__ __launch_bounds__(512) void final_kernel(
    const float* __restrict__ bpart, float* __restrict__ out) {
  int t = threadIdx.x;  // 512 threads = 8 waves
  float v = bpart[t];
  #pragma unroll
  for (int m = 1; m < 64; m <<= 1) v += __shfl_xor(v, m, 64);
  __shared__ float r2[8];
  if ((t & 63) == 0) r2[t >> 6] = v;
  __syncthreads();
  if (t == 0) {
    float s = 0.f;
    #pragma unroll
    for (int w = 0; w < 8; ++w) s += r2[w];
    out[0] = s / (float)NROWS;
  }
}

// ---------------- Launcher --------------------------------------------------
extern "C" void kernel_launch(void* const* d_in, const int* in_sizes, int n_in,
                              void* d_out, int out_size, void* d_ws, size_t ws_size,
                              hipStream_t stream) {
  const float* a = (const float*)d_in[0];
  const float* b = (const float*)d_in[1];
  float* out = (float*)d_out;
  char* ws = (char*)d_ws;

  char* zb = ws;                                            // 4 MiB
  float* selfdot = (float*)(ws + (size_t)NROWS * ROWB);     // 32 KiB
  float* s_part = selfdot + NROWS;                          // 2 MiB [8192][64]
  float* bpart = s_part + (size_t)NROWS * SSTRIDE;          // 2 KiB

  hipLaunchKernelGGL(norm_kernel, dim3(NROWS / 4), dim3(256), 0, stream,
                     a, b, zb, selfdot);
  hipLaunchKernelGGL(sim_kernel, dim3(64, 11), dim3(256), 0, stream,
                     zb, s_part);
  hipLaunchKernelGGL(rowterm_kernel, dim3(512), dim3(256), 0, stream,
                     zb, s_part, selfdot, bpart);
  hipLaunchKernelGGL(final_kernel, dim3(1), dim3(512), 0, stream, bpart, out);
}